// Round 12
// baseline (5617.308 us; speedup 1.0000x reference)
//
#include <hip/hip_runtime.h>
#include <stdint.h>

#define T_STEPS 2048
#define BATCH   64
#define IN_SZ   256
#define HID     512
#define FANG    768          // HID + IN_SZ
#define NLAYER  2
#define TOT_STEPS (T_STEPS*NLAYER)

typedef _Float16 h2 __attribute__((ext_vector_type(2)));
typedef unsigned long long u64;
typedef unsigned int u32;

__device__ __forceinline__ float dot2f(h2 a, h2 b, float c) {
#if __has_builtin(__builtin_amdgcn_fdot2)
    return __builtin_amdgcn_fdot2(a, b, c, false);
#else
    return c + (float)a.x * (float)b.x + (float)a.y * (float)b.y;
#endif
}

__device__ __forceinline__ u32 packh2(float a, float b) {
    h2 t{(_Float16)a, (_Float16)b};
    return __builtin_bit_cast(u32, t);
}
__device__ __forceinline__ h2 bch2(float v) { return __builtin_bit_cast(h2, v); }
__device__ __forceinline__ h2 bch2u(u32 v)  { return __builtin_bit_cast(h2, v); }

// Round-2/6/8/10/11-PROVEN exchange: relaxed agent-scope atomics on one u64
// (tag32 | 2xfp16). Tag and data in ONE word -> no fences needed.
__device__ __forceinline__ u64 ld_llc(const u64* p) {
    return __hip_atomic_load(p, __ATOMIC_RELAXED, __HIP_MEMORY_SCOPE_AGENT);
}
__device__ __forceinline__ void st_llc(u64* p, u64 v) {
    __hip_atomic_store(p, v, __ATOMIC_RELAXED, __HIP_MEMORY_SCOPE_AGENT);
}

// Raw workgroup barrier WITHOUT the vmcnt(0) drain of __syncthreads.
// LDS producer->consumer only needs lgkmcnt(0) (ds_write completion) before
// s_barrier; in-flight GLOBAL loads (poll probes, xproj prefetch) may stay
// outstanding across it. Memory clobbers fence compiler code motion.
__device__ __forceinline__ void wg_barrier() {
    asm volatile("s_waitcnt lgkmcnt(0)" ::: "memory");
    __builtin_amdgcn_s_barrier();
    asm volatile("" ::: "memory");
}

// DPP adds (compile-time ctrl). 16-lane reduce chain (r6/r11-proven):
// xor1, xor2 (quad sums) then row_ror:4, row_ror:8 -- lanes 0..3 (mod 16)
// end with the full 16-lane sum. Act lanes are c<4 = lanes 0..3 mod 16.
template<int CTRL>
__device__ __forceinline__ float dpp_add(float x) {
    int xi = __builtin_bit_cast(int, x);
    int yi = __builtin_amdgcn_update_dpp(0, xi, CTRL, 0xf, 0xf, true);
    return x + __builtin_bit_cast(float, yi);
}
__device__ __forceinline__ float reduce16(float x) {
    x = dpp_add<0xB1>(x);          // quad xor1
    x = dpp_add<0x4E>(x);          // quad xor2
    x = dpp_add<0x124>(x);         // row_ror:4
    x = dpp_add<0x128>(x);         // row_ror:8
    return x;
}

// Overflow-free activations: rcp is the HW approx (~1ulp, way inside the
// 5.2e-3 budget). tanh via e^{-2|x|} in (0,1] -> never overflows, no clamps.
__device__ __forceinline__ float rcpf(float x) { return __builtin_amdgcn_rcpf(x); }
__device__ __forceinline__ float tanh_pos(float ax) {   // tanh(|x|)
    float t = __expf(-2.0f * ax);
    return (1.0f - t) * rcpf(1.0f + t);
}

// -------------------------------------------------------------------------
// Kernel 1: Xproj — persistent-B fp16 dot2 GEMM (proven). fp16-packed out.
// -------------------------------------------------------------------------
__global__ __launch_bounds__(256) void xproj_kernel(
    const float* __restrict__ input,
    const float* __restrict__ gate_w,
    const float* __restrict__ gate_b,
    u32* __restrict__ xp16)
{
    __shared__ _Float16 Bs[64][264];
    __shared__ _Float16 As[64][264];

    const int jt = blockIdx.x;         // 0..7
    const int mg = blockIdx.y;         // 0..63
    const int tid = threadIdx.x;
    const int tx = tid & 15, ty = tid >> 4;
    const int j0 = jt * 64;

    #pragma unroll
    for (int l = 0; l < 16; ++l) {
        int e = tid + l * 256;
        int i = e >> 6, kq = e & 63;
        float4 v = *(const float4*)&gate_w[(size_t)(j0 + i) * FANG + HID + kq * 4];
        *(h2*)&Bs[i][kq * 4]     = h2{(_Float16)v.x, (_Float16)v.y};
        *(h2*)&Bs[i][kq * 4 + 2] = h2{(_Float16)v.z, (_Float16)v.w};
    }

    const float4 gb = *(const float4*)&gate_b[j0 + tx * 4];

    for (int mt = 0; mt < 32; ++mt) {
        const int m0 = (mg * 32 + mt) * 64;
        __syncthreads();
        #pragma unroll
        for (int l = 0; l < 16; ++l) {
            int e = tid + l * 256;
            int i = e >> 6, kq = e & 63;
            float4 v = *(const float4*)&input[(size_t)(m0 + i) * IN_SZ + kq * 4];
            *(h2*)&As[i][kq * 4]     = h2{(_Float16)v.x, (_Float16)v.y};
            *(h2*)&As[i][kq * 4 + 2] = h2{(_Float16)v.z, (_Float16)v.w};
        }
        __syncthreads();

        float acc[4][4] = {};
        #pragma unroll
        for (int q = 0; q < 32; ++q) {
            const int k = ((q + tx) & 31) * 8;
            float4 av[4], bv[4];
            #pragma unroll
            for (int i = 0; i < 4; ++i)  av[i] = *(const float4*)&As[ty * 4 + i][k];
            #pragma unroll
            for (int jj = 0; jj < 4; ++jj) bv[jj] = *(const float4*)&Bs[tx * 4 + jj][k];
            #pragma unroll
            for (int i = 0; i < 4; ++i) {
                h2 a0 = bch2(av[i].x), a1 = bch2(av[i].y);
                h2 a2 = bch2(av[i].z), a3 = bch2(av[i].w);
                #pragma unroll
                for (int jj = 0; jj < 4; ++jj) {
                    acc[i][jj] = dot2f(a0, bch2(bv[jj].x), acc[i][jj]);
                    acc[i][jj] = dot2f(a1, bch2(bv[jj].y), acc[i][jj]);
                    acc[i][jj] = dot2f(a2, bch2(bv[jj].z), acc[i][jj]);
                    acc[i][jj] = dot2f(a3, bch2(bv[jj].w), acc[i][jj]);
                }
            }
        }

        #pragma unroll
        for (int i = 0; i < 4; ++i) {
            uint2 ww = { packh2(acc[i][0] + gb.x, acc[i][1] + gb.y),
                         packh2(acc[i][2] + gb.z, acc[i][3] + gb.w) };
            *(uint2*)&xp16[(size_t)(m0 + ty * 4 + i) * 256 + ((j0 + tx * 4) >> 1)] = ww;
        }
    }
}

// -------------------------------------------------------------------------
// Kernel 2: recurrence. 256 WGs = 4 slices x 64 batch, 512 threads, 1/CU.
// r11 dataflow (4-row reuse: 4 ds_read_b128 + 64 dot2 per thread/step),
// r11 weights (64 h2, under 128-arch cap), r11 exchange (tagged u64).
// ROUND-12 latency attacks:
//  (1) 2-deep pipelined poll -> sampling period ~RT/2 (vmcnt(1) checks);
//  (2) ONE raw barrier per step (lgkmcnt(0)+s_barrier, NO vmcnt drain):
//      poll probes / xproj loads stay in flight across it. Safety: pollers'
//      ds_writes + previous step's bypass write are lgkm-drained pre-bar;
//      all dot reads follow it; double-buffered hl makes every other
//      write/read pair address-disjoint (r2/r11 proof shape).
//  (3) overflow-free act chain (1 exp + rcp for sigmoid, tanh via
//      e^{-2|x|}+copysign, no clamps) -> shorter serial dependency.
// -------------------------------------------------------------------------
__global__ __launch_bounds__(512, 2) void lstm_kernel(
    const float* __restrict__ gate_w,
    const u32* __restrict__ xp16,
    u64* __restrict__ hx)
{
    const int blk = blockIdx.x;     // 0..255
    const int s   = blk >> 6;       // slice 0..3 (owns rows s*128..+128)
    const int b   = blk & 63;       // batch row
    const int tid = threadIdx.x;    // 0..511
    const int g   = tid >> 4;       // row group 0..31 (rows g*4..+3 of slice)
    const int c   = tid & 15;       // k-lane
    const int j0  = s * 128 + g * 4;

    __shared__ u32 hl[2][256];      // h words, addr(w) = w, double-buffered

    // weights: w2[rr*16 + u*4 + m] <-> h2-word ((s+u)&3)*64 + c*4 + m
    h2 w2[64];
    #pragma unroll
    for (int u = 0; u < 4; ++u) {
        const int kb = (((s + u) & 3) * 64 + c * 4) * 2;   // h-value index
        #pragma unroll
        for (int rr = 0; rr < 4; ++rr) {
            const float* wr = gate_w + (size_t)(j0 + rr) * FANG + kb;
            float4 v0 = *(const float4*)(wr);
            float4 v1 = *(const float4*)(wr + 4);
            w2[rr * 16 + u * 4 + 0] = h2{(_Float16)v0.x, (_Float16)v0.y};
            w2[rr * 16 + u * 4 + 1] = h2{(_Float16)v0.z, (_Float16)v0.w};
            w2[rr * 16 + u * 4 + 2] = h2{(_Float16)v1.x, (_Float16)v1.y};
            w2[rr * 16 + u * 4 + 3] = h2{(_Float16)v1.z, (_Float16)v1.w};
        }
    }

    // poller mapping (tid<192): remote slices only; LDS addr == word index
    const int si  = tid >> 6;                 // 0..2
    const int qs  = si + (si >= s);           // skip own slice
    const int prw = qs * 64 + (tid & 63);

    if (tid < 256) hl[0][tid] = 0;            // h = 0 for step 0

    float cval = 0.0f;                        // cell state (lanes c<4)

    for (int st = 0; st < TOT_STEPS; ++st) {
        const int t   = st & (T_STEPS - 1);
        const int buf = st & 1;

        // xproj word for this act-lane's row (stays in flight across barrier)
        u32 xw = 0;
        if (c < 4) xw = xp16[((size_t)t * BATCH + b) * 256 + s * 64 + g * 2 + (c >> 1)];

        // ---- 2-deep pipelined poll + stage (tid<192) ----
        if (tid < 192) {
            const u64* pp = hx + ((size_t)buf * BATCH + b) * 256 + prw;
            u64 va = ld_llc(pp);
            u64 vb = ld_llc(pp);
            u64 v;
            int spin = 0;
            for (;;) {
                if ((u32)(va >> 32) == (u32)st) { v = va; break; }
                va = ld_llc(pp);
                if ((u32)(vb >> 32) == (u32)st) { v = vb; break; }
                vb = ld_llc(pp);
                if (++spin > (1 << 15)) { v = va; break; }   // safety bailout
            }
            hl[buf][prw] = (u32)v;
        }

        wg_barrier();   // the ONLY barrier per step (no vmcnt drain)

        // ---- full dot: 4 reads (own + 3 remote) x 16 dot2 ----
        float a0 = 0.f, a1 = 0.f, a2 = 0.f, a3 = 0.f;
        #pragma unroll
        for (int u = 0; u < 4; ++u) {
            float4 rv = *(const float4*)&hl[buf][((s + u) & 3) * 64 + c * 4];
            h2 x0 = bch2(rv.x), x1 = bch2(rv.y), x2 = bch2(rv.z), x3 = bch2(rv.w);
            a0 = dot2f(w2[     u*4+0], x0, a0); a0 = dot2f(w2[     u*4+1], x1, a0);
            a0 = dot2f(w2[     u*4+2], x2, a0); a0 = dot2f(w2[     u*4+3], x3, a0);
            a1 = dot2f(w2[16 + u*4+0], x0, a1); a1 = dot2f(w2[16 + u*4+1], x1, a1);
            a1 = dot2f(w2[16 + u*4+2], x2, a1); a1 = dot2f(w2[16 + u*4+3], x3, a1);
            a2 = dot2f(w2[32 + u*4+0], x0, a2); a2 = dot2f(w2[32 + u*4+1], x1, a2);
            a2 = dot2f(w2[32 + u*4+2], x2, a2); a2 = dot2f(w2[32 + u*4+3], x3, a2);
            a3 = dot2f(w2[48 + u*4+0], x0, a3); a3 = dot2f(w2[48 + u*4+1], x1, a3);
            a3 = dot2f(w2[48 + u*4+2], x2, a3); a3 = dot2f(w2[48 + u*4+3], x3, a3);
        }

        // 16-lane reduce, pure DPP; lanes c<4 get full sums
        a0 = reduce16(a0);
        a1 = reduce16(a1);
        a2 = reduce16(a2);
        a3 = reduce16(a3);

        float hf = 0.0f;
        if (c < 4) {
            float p = (c == 0) ? a0 : (c == 1) ? a1 : (c == 2) ? a2 : a3;
            h2 xp = bch2u(xw);
            float gg = p + (float)((c & 1) ? xp.y : xp.x);
            float et = __expf(-gg);                       // e^{-g}
            float sg = rcpf(1.0f + et);                   // sigmoid(g)
            float ch = copysignf(tanh_pos(fabsf(gg)), gg);// tanh(g)
            cval = (cval + ch) * sg;                      // c*s + ch*s
            float th = copysignf(tanh_pos(fabsf(cval)), cval);
            hf = th * sg;
        }
        // pack row pair: lanes (c=0,c=1) and (c=2,c=3) hold consecutive rows
        float hfo = __shfl_down(hf, 1);
        if (c == 0 || c == 2) {
            const int w = s * 64 + g * 2 + (c >> 1);
            u32 pk = packh2(hf, hfo);
            st_llc(hx + ((size_t)((st + 1) & 1) * BATCH + b) * 256 + w,
                   (u64)pk | ((u64)(u32)(st + 1) << 32));
            hl[buf ^ 1][w] = pk;           // local bypass for own slice
        }
        // no trailing barrier: bypass writes hl[buf^1]; the next step's
        // barrier (lgkmcnt(0)+s_barrier) orders them before any read.
    }
}

// -------------------------------------------------------------------------
// Kernel 3: output = h_final @ out_w.T + out_b. Final h in hx buffer 0
// (TOT_STEPS even), 2 fp16 per word's low 32 bits.
// -------------------------------------------------------------------------
__global__ __launch_bounds__(256) void out_kernel(
    const u64* __restrict__ hx,
    const float* __restrict__ out_w,
    const float* __restrict__ out_b,
    float* __restrict__ out)
{
    const int b  = blockIdx.x;    // 64
    const int jt = threadIdx.x;   // 256
    __shared__ float hrow[512];

    {
        u64 v = hx[(size_t)b * 256 + jt];
        h2 pr = bch2u((u32)v);
        hrow[2 * jt]     = (float)pr.x;
        hrow[2 * jt + 1] = (float)pr.y;
    }
    __syncthreads();

    float acc = out_b[jt];
    const float* wr = out_w + (size_t)jt * HID;
    #pragma unroll 8
    for (int k = 0; k < HID; ++k)
        acc += hrow[k] * wr[k];
    out[(size_t)b * IN_SZ + jt] = acc;
}

// -------------------------------------------------------------------------
extern "C" void kernel_launch(void* const* d_in, const int* in_sizes, int n_in,
                              void* d_out, int out_size, void* d_ws, size_t ws_size,
                              hipStream_t stream)
{
    const float* input  = (const float*)d_in[0];
    const float* gate_w = (const float*)d_in[1];
    const float* gate_b = (const float*)d_in[2];
    const float* out_w  = (const float*)d_in[3];
    const float* out_b  = (const float*)d_in[4];
    float* out = (float*)d_out;

    // ws layout: Xproj fp16-packed (128 MB) | hx [2][64][256] u64 (256 KB)
    u32* xp16 = (u32*)d_ws;
    const size_t xbytes = (size_t)T_STEPS * BATCH * 256 * sizeof(u32);
    u64* hx = (u64*)((char*)d_ws + xbytes);

    // zero the exchange every launch: tag 0 == initial h = 0; graph replays
    // must never see stale tags.
    (void)hipMemsetAsync(hx, 0, (size_t)2 * BATCH * 256 * sizeof(u64), stream);

    dim3 g1(8, 64);
    xproj_kernel<<<g1, 256, 0, stream>>>(input, gate_w, gate_b, xp16);
    lstm_kernel<<<256, 512, 0, stream>>>(gate_w, xp16, hx);
    out_kernel<<<64, 256, 0, stream>>>(hx, out_w, out_b, out);
}

// Round 13
// 5064.333 us; speedup vs baseline: 1.1092x; 1.1092x over previous
//
#include <hip/hip_runtime.h>
#include <stdint.h>

#define T_STEPS 2048
#define BATCH   64
#define IN_SZ   256
#define HID     512
#define FANG    768          // HID + IN_SZ
#define NLAYER  2
#define TOT_STEPS (T_STEPS*NLAYER)

typedef _Float16 h2 __attribute__((ext_vector_type(2)));
typedef unsigned long long u64;
typedef unsigned int u32;

__device__ __forceinline__ float dot2f(h2 a, h2 b, float c) {
#if __has_builtin(__builtin_amdgcn_fdot2)
    return __builtin_amdgcn_fdot2(a, b, c, false);
#else
    return c + (float)a.x * (float)b.x + (float)a.y * (float)b.y;
#endif
}

__device__ __forceinline__ u32 packh2(float a, float b) {
    h2 t{(_Float16)a, (_Float16)b};
    return __builtin_bit_cast(u32, t);
}
__device__ __forceinline__ h2 bch2(float v) { return __builtin_bit_cast(h2, v); }
__device__ __forceinline__ h2 bch2u(u32 v)  { return __builtin_bit_cast(h2, v); }

// Round-2/6/8/10/11-PROVEN exchange: relaxed agent-scope atomics on one u64
// (tag32 | 2xfp16). Tag and data in ONE word -> no fences needed.
__device__ __forceinline__ u64 ld_llc(const u64* p) {
    return __hip_atomic_load(p, __ATOMIC_RELAXED, __HIP_MEMORY_SCOPE_AGENT);
}
__device__ __forceinline__ void st_llc(u64* p, u64 v) {
    __hip_atomic_store(p, v, __ATOMIC_RELAXED, __HIP_MEMORY_SCOPE_AGENT);
}

// Raw workgroup barrier WITHOUT the vmcnt(0) drain of __syncthreads.
// LDS producer->consumer needs only lgkmcnt(0) (ds_write completion) before
// s_barrier; in-flight GLOBAL loads (poll probe, xproj word) stay
// outstanding across it -- their latency hides under the following dot.
__device__ __forceinline__ void wg_barrier() {
    asm volatile("s_waitcnt lgkmcnt(0)" ::: "memory");
    __builtin_amdgcn_s_barrier();
    asm volatile("" ::: "memory");
}

// DPP adds (compile-time ctrl). 16-lane reduce chain (r6/r11-proven):
// xor1, xor2 (quad sums) then row_ror:4, row_ror:8 -- lanes 0..3 (mod 16)
// end with the full 16-lane sum. Act lanes are c<4 = lanes 0..3 mod 16.
template<int CTRL>
__device__ __forceinline__ float dpp_add(float x) {
    int xi = __builtin_bit_cast(int, x);
    int yi = __builtin_amdgcn_update_dpp(0, xi, CTRL, 0xf, 0xf, true);
    return x + __builtin_bit_cast(float, yi);
}
__device__ __forceinline__ float reduce16(float x) {
    x = dpp_add<0xB1>(x);          // quad xor1
    x = dpp_add<0x4E>(x);          // quad xor2
    x = dpp_add<0x124>(x);         // row_ror:4
    x = dpp_add<0x128>(x);         // row_ror:8
    return x;
}

// Overflow-free activations (r12-verified numerics, absmax unchanged 1e-3):
// sigmoid = rcp(1+e^{-g}); tanh(|x|) = (1-e^{-2|x|}) * rcp(1+e^{-2|x|}).
__device__ __forceinline__ float rcpf(float x) { return __builtin_amdgcn_rcpf(x); }
__device__ __forceinline__ float tanh_pos(float ax) {
    float t = __expf(-2.0f * ax);
    return (1.0f - t) * rcpf(1.0f + t);
}

// -------------------------------------------------------------------------
// Kernel 1: Xproj — persistent-B fp16 dot2 GEMM (proven). fp16-packed out.
// -------------------------------------------------------------------------
__global__ __launch_bounds__(256) void xproj_kernel(
    const float* __restrict__ input,
    const float* __restrict__ gate_w,
    const float* __restrict__ gate_b,
    u32* __restrict__ xp16)
{
    __shared__ _Float16 Bs[64][264];
    __shared__ _Float16 As[64][264];

    const int jt = blockIdx.x;         // 0..7
    const int mg = blockIdx.y;         // 0..63
    const int tid = threadIdx.x;
    const int tx = tid & 15, ty = tid >> 4;
    const int j0 = jt * 64;

    #pragma unroll
    for (int l = 0; l < 16; ++l) {
        int e = tid + l * 256;
        int i = e >> 6, kq = e & 63;
        float4 v = *(const float4*)&gate_w[(size_t)(j0 + i) * FANG + HID + kq * 4];
        *(h2*)&Bs[i][kq * 4]     = h2{(_Float16)v.x, (_Float16)v.y};
        *(h2*)&Bs[i][kq * 4 + 2] = h2{(_Float16)v.z, (_Float16)v.w};
    }

    const float4 gb = *(const float4*)&gate_b[j0 + tx * 4];

    for (int mt = 0; mt < 32; ++mt) {
        const int m0 = (mg * 32 + mt) * 64;
        __syncthreads();
        #pragma unroll
        for (int l = 0; l < 16; ++l) {
            int e = tid + l * 256;
            int i = e >> 6, kq = e & 63;
            float4 v = *(const float4*)&input[(size_t)(m0 + i) * IN_SZ + kq * 4];
            *(h2*)&As[i][kq * 4]     = h2{(_Float16)v.x, (_Float16)v.y};
            *(h2*)&As[i][kq * 4 + 2] = h2{(_Float16)v.z, (_Float16)v.w};
        }
        __syncthreads();

        float acc[4][4] = {};
        #pragma unroll
        for (int q = 0; q < 32; ++q) {
            const int k = ((q + tx) & 31) * 8;
            float4 av[4], bv[4];
            #pragma unroll
            for (int i = 0; i < 4; ++i)  av[i] = *(const float4*)&As[ty * 4 + i][k];
            #pragma unroll
            for (int jj = 0; jj < 4; ++jj) bv[jj] = *(const float4*)&Bs[tx * 4 + jj][k];
            #pragma unroll
            for (int i = 0; i < 4; ++i) {
                h2 a0 = bch2(av[i].x), a1 = bch2(av[i].y);
                h2 a2 = bch2(av[i].z), a3 = bch2(av[i].w);
                #pragma unroll
                for (int jj = 0; jj < 4; ++jj) {
                    acc[i][jj] = dot2f(a0, bch2(bv[jj].x), acc[i][jj]);
                    acc[i][jj] = dot2f(a1, bch2(bv[jj].y), acc[i][jj]);
                    acc[i][jj] = dot2f(a2, bch2(bv[jj].z), acc[i][jj]);
                    acc[i][jj] = dot2f(a3, bch2(bv[jj].w), acc[i][jj]);
                }
            }
        }

        #pragma unroll
        for (int i = 0; i < 4; ++i) {
            uint2 ww = { packh2(acc[i][0] + gb.x, acc[i][1] + gb.y),
                         packh2(acc[i][2] + gb.z, acc[i][3] + gb.w) };
            *(uint2*)&xp16[(size_t)(m0 + ty * 4 + i) * 256 + ((j0 + tx * 4) >> 1)] = ww;
        }
    }
}

// -------------------------------------------------------------------------
// Kernel 2: recurrence. 256 WGs = 4 slices x 64 batch, 512 threads, 1/CU.
// r11 two-phase structure (proven best): probe -> bar1 -> own-slice dot
// (hides probe/detect RT) -> detect+stage -> bar2 -> remote dot -> reduce
// -> act -> store. Round-13 deltas, each independently safe:
//  (1) wg_barrier (lgkm-only) at BOTH barriers: no vmcnt(0) drain, so the
//      pre-issued probe + xw loads complete under the own-dot;
//  (2) wave-balanced pollers: lane<24 in every wave (8x24=192) -> equal
//      per-wave work -> less barrier-convergence skew;
//  (3) overflow-free short act chain (r12-verified numerics);
//  (4) producer: st_llc first (remote critical path), LDS bypass second.
// Exchange/back-pressure chain identical to r10/r11 (proven).
// -------------------------------------------------------------------------
__global__ __launch_bounds__(512, 2) void lstm_kernel(
    const float* __restrict__ gate_w,
    const u32* __restrict__ xp16,
    u64* __restrict__ hx)
{
    const int blk  = blockIdx.x;     // 0..255
    const int s    = blk >> 6;       // slice 0..3 (owns rows s*128..+128)
    const int b    = blk & 63;       // batch row
    const int tid  = threadIdx.x;    // 0..511
    const int g    = tid >> 4;       // row group 0..31 (rows g*4..+3 of slice)
    const int c    = tid & 15;       // k-lane
    const int wv   = tid >> 6;       // wave 0..7
    const int lane = tid & 63;
    const int j0   = s * 128 + g * 4;

    __shared__ u32 hl[2][256];      // h words, addr(w) = w, double-buffered

    // weights: w2[rr*16 + u*4 + m] <-> h2-word ((s+u)&3)*64 + c*4 + m
    h2 w2[64];
    #pragma unroll
    for (int u = 0; u < 4; ++u) {
        const int kb = (((s + u) & 3) * 64 + c * 4) * 2;   // h-value index
        #pragma unroll
        for (int rr = 0; rr < 4; ++rr) {
            const float* wr = gate_w + (size_t)(j0 + rr) * FANG + kb;
            float4 v0 = *(const float4*)(wr);
            float4 v1 = *(const float4*)(wr + 4);
            w2[rr * 16 + u * 4 + 0] = h2{(_Float16)v0.x, (_Float16)v0.y};
            w2[rr * 16 + u * 4 + 1] = h2{(_Float16)v0.z, (_Float16)v0.w};
            w2[rr * 16 + u * 4 + 2] = h2{(_Float16)v1.x, (_Float16)v1.y};
            w2[rr * 16 + u * 4 + 3] = h2{(_Float16)v1.z, (_Float16)v1.w};
        }
    }

    // wave-balanced poller mapping: lane<24 in each wave handles poll index
    // i = wv*24 + lane (192 total); remote slices only.
    const bool poller = (lane < 24);
    const int  pi  = wv * 24 + lane;          // 0..191
    const int  si  = pi >> 6;                 // 0..2
    const int  qs  = si + (si >= s);          // skip own slice
    const int  prw = qs * 64 + (pi & 63);     // polled word = LDS addr

    if (tid < 256) hl[0][tid] = 0;            // h = 0 for step 0

    float cval = 0.0f;                        // cell state (lanes c<4)

    for (int st = 0; st < TOT_STEPS; ++st) {
        const int t   = st & (T_STEPS - 1);
        const int buf = st & 1;

        // xproj word for this act-lane's row (in flight across bar1)
        u32 xw = 0;
        if (c < 4) xw = xp16[((size_t)t * BATCH + b) * 256 + s * 64 + g * 2 + (c >> 1)];

        // first probe, in flight across bar1 + own-slice dot
        const u64* pp = hx + ((size_t)buf * BATCH + b) * 256 + prw;
        u64 pv = 0;
        if (poller) pv = ld_llc(pp);

        wg_barrier();   // bar1 (lgkm-only): last step's bypass published

        // ---- own-slice dot: 1 read, 16 dot2 (hides probe RT) ----
        float a0 = 0.f, a1 = 0.f, a2 = 0.f, a3 = 0.f;
        {
            float4 rv = *(const float4*)&hl[buf][s * 64 + c * 4];
            h2 x0 = bch2(rv.x), x1 = bch2(rv.y), x2 = bch2(rv.z), x3 = bch2(rv.w);
            a0 = dot2f(w2[ 0], x0, a0); a0 = dot2f(w2[ 1], x1, a0);
            a0 = dot2f(w2[ 2], x2, a0); a0 = dot2f(w2[ 3], x3, a0);
            a1 = dot2f(w2[16], x0, a1); a1 = dot2f(w2[17], x1, a1);
            a1 = dot2f(w2[18], x2, a1); a1 = dot2f(w2[19], x3, a1);
            a2 = dot2f(w2[32], x0, a2); a2 = dot2f(w2[33], x1, a2);
            a2 = dot2f(w2[34], x2, a2); a2 = dot2f(w2[35], x3, a2);
            a3 = dot2f(w2[48], x0, a3); a3 = dot2f(w2[49], x1, a3);
            a3 = dot2f(w2[50], x2, a3); a3 = dot2f(w2[51], x3, a3);
        }

        // ---- detect + stage the remote slices ----
        if (poller) {
            u64 v = pv;
            int spin = 0;
            while ((u32)(v >> 32) != (u32)st) {
                v = ld_llc(pp);
                if (++spin > (1 << 16)) break;        // safety bailout
                if (spin > 64) __builtin_amdgcn_s_sleep(1);
            }
            hl[buf][prw] = (u32)v;
        }
        wg_barrier();   // bar2 (lgkm-only): remote h staged

        // ---- remote dot: 3 reads x 16 dot2 ----
        #pragma unroll
        for (int u = 1; u < 4; ++u) {
            float4 rv = *(const float4*)&hl[buf][((s + u) & 3) * 64 + c * 4];
            h2 x0 = bch2(rv.x), x1 = bch2(rv.y), x2 = bch2(rv.z), x3 = bch2(rv.w);
            a0 = dot2f(w2[     u*4+0], x0, a0); a0 = dot2f(w2[     u*4+1], x1, a0);
            a0 = dot2f(w2[     u*4+2], x2, a0); a0 = dot2f(w2[     u*4+3], x3, a0);
            a1 = dot2f(w2[16 + u*4+0], x0, a1); a1 = dot2f(w2[16 + u*4+1], x1, a1);
            a1 = dot2f(w2[16 + u*4+2], x2, a1); a1 = dot2f(w2[16 + u*4+3], x3, a1);
            a2 = dot2f(w2[32 + u*4+0], x0, a2); a2 = dot2f(w2[32 + u*4+1], x1, a2);
            a2 = dot2f(w2[32 + u*4+2], x2, a2); a2 = dot2f(w2[32 + u*4+3], x3, a2);
            a3 = dot2f(w2[48 + u*4+0], x0, a3); a3 = dot2f(w2[48 + u*4+1], x1, a3);
            a3 = dot2f(w2[48 + u*4+2], x2, a3); a3 = dot2f(w2[48 + u*4+3], x3, a3);
        }

        // 16-lane reduce, pure DPP; lanes c<4 get full sums
        a0 = reduce16(a0);
        a1 = reduce16(a1);
        a2 = reduce16(a2);
        a3 = reduce16(a3);

        float hf = 0.0f;
        if (c < 4) {
            float p = (c == 0) ? a0 : (c == 1) ? a1 : (c == 2) ? a2 : a3;
            h2 xp = bch2u(xw);
            float gg = p + (float)((c & 1) ? xp.y : xp.x);
            float et = __expf(-gg);                        // e^{-g}
            float sg = rcpf(1.0f + et);                    // sigmoid(g)
            float ch = copysignf(tanh_pos(fabsf(gg)), gg); // tanh(g)
            cval = (cval + ch) * sg;                       // c*s + ch*s
            float th = copysignf(tanh_pos(fabsf(cval)), cval);
            hf = th * sg;
        }
        // pack row pair: lanes (c=0,c=1) and (c=2,c=3) hold consecutive rows
        float hfo = __shfl_down(hf, 1);
        if (c == 0 || c == 2) {
            const int w = s * 64 + g * 2 + (c >> 1);
            u32 pk = packh2(hf, hfo);
            // remote critical path first, local bypass second
            st_llc(hx + ((size_t)((st + 1) & 1) * BATCH + b) * 256 + w,
                   (u64)pk | ((u64)(u32)(st + 1) << 32));
            hl[buf ^ 1][w] = pk;
        }
        // no trailing barrier: bypass writes hl[buf^1]; next step's bar1
        // (lgkmcnt(0)+s_barrier) orders them before any read.
    }
}

// -------------------------------------------------------------------------
// Kernel 3: output = h_final @ out_w.T + out_b. Final h in hx buffer 0
// (TOT_STEPS even), 2 fp16 per word's low 32 bits.
// -------------------------------------------------------------------------
__global__ __launch_bounds__(256) void out_kernel(
    const u64* __restrict__ hx,
    const float* __restrict__ out_w,
    const float* __restrict__ out_b,
    float* __restrict__ out)
{
    const int b  = blockIdx.x;    // 64
    const int jt = threadIdx.x;   // 256
    __shared__ float hrow[512];

    {
        u64 v = hx[(size_t)b * 256 + jt];
        h2 pr = bch2u((u32)v);
        hrow[2 * jt]     = (float)pr.x;
        hrow[2 * jt + 1] = (float)pr.y;
    }
    __syncthreads();

    float acc = out_b[jt];
    const float* wr = out_w + (size_t)jt * HID;
    #pragma unroll 8
    for (int k = 0; k < HID; ++k)
        acc += hrow[k] * wr[k];
    out[(size_t)b * IN_SZ + jt] = acc;
}

// -------------------------------------------------------------------------
extern "C" void kernel_launch(void* const* d_in, const int* in_sizes, int n_in,
                              void* d_out, int out_size, void* d_ws, size_t ws_size,
                              hipStream_t stream)
{
    const float* input  = (const float*)d_in[0];
    const float* gate_w = (const float*)d_in[1];
    const float* gate_b = (const float*)d_in[2];
    const float* out_w  = (const float*)d_in[3];
    const float* out_b  = (const float*)d_in[4];
    float* out = (float*)d_out;

    // ws layout: Xproj fp16-packed (128 MB) | hx [2][64][256] u64 (256 KB)
    u32* xp16 = (u32*)d_ws;
    const size_t xbytes = (size_t)T_STEPS * BATCH * 256 * sizeof(u32);
    u64* hx = (u64*)((char*)d_ws + xbytes);

    // zero the exchange every launch: tag 0 == initial h = 0; graph replays
    // must never see stale tags.
    (void)hipMemsetAsync(hx, 0, (size_t)2 * BATCH * 256 * sizeof(u64), stream);

    dim3 g1(8, 64);
    xproj_kernel<<<g1, 256, 0, stream>>>(input, gate_w, gate_b, xp16);
    lstm_kernel<<<256, 512, 0, stream>>>(gate_w, xp16, hx);
    out_kernel<<<64, 256, 0, stream>>>(hx, out_w, out_b, out);
}

// Round 14
// 4886.865 us; speedup vs baseline: 1.1495x; 1.0363x over previous
//
#include <hip/hip_runtime.h>
#include <stdint.h>

#define T_STEPS 2048
#define BATCH   64
#define IN_SZ   256
#define HID     512
#define FANG    768          // HID + IN_SZ
#define NLAYER  2
#define TOT_STEPS (T_STEPS*NLAYER)

typedef _Float16 h2 __attribute__((ext_vector_type(2)));
typedef _Float16 f16x8 __attribute__((ext_vector_type(8)));
typedef float    f32x4 __attribute__((ext_vector_type(4)));
typedef unsigned long long u64;
typedef unsigned int u32;

__device__ __forceinline__ float dot2f(h2 a, h2 b, float c) {
#if __has_builtin(__builtin_amdgcn_fdot2)
    return __builtin_amdgcn_fdot2(a, b, c, false);
#else
    return c + (float)a.x * (float)b.x + (float)a.y * (float)b.y;
#endif
}

__device__ __forceinline__ u32 packh2(float a, float b) {
    h2 t{(_Float16)a, (_Float16)b};
    return __builtin_bit_cast(u32, t);
}
__device__ __forceinline__ h2 bch2(float v) { return __builtin_bit_cast(h2, v); }
__device__ __forceinline__ h2 bch2u(u32 v)  { return __builtin_bit_cast(h2, v); }

// PROVEN exchange (r2/r6/r8/r10/r11/r13): relaxed agent-scope atomics on one
// u64 (tag32 | 2xfp16). Tag and data in ONE word -> no fences needed.
__device__ __forceinline__ u64 ld_llc(const u64* p) {
    return __hip_atomic_load(p, __ATOMIC_RELAXED, __HIP_MEMORY_SCOPE_AGENT);
}
__device__ __forceinline__ void st_llc(u64* p, u64 v) {
    __hip_atomic_store(p, v, __ATOMIC_RELAXED, __HIP_MEMORY_SCOPE_AGENT);
}

// Raw workgroup barrier WITHOUT the vmcnt(0) drain of __syncthreads (r13).
__device__ __forceinline__ void wg_barrier() {
    asm volatile("s_waitcnt lgkmcnt(0)" ::: "memory");
    __builtin_amdgcn_s_barrier();
    asm volatile("" ::: "memory");
}

// DPP 16-lane reduce (r6/r11-proven): lanes 0..3 mod 16 get the full sum.
template<int CTRL>
__device__ __forceinline__ float dpp_add(float x) {
    int xi = __builtin_bit_cast(int, x);
    int yi = __builtin_amdgcn_update_dpp(0, xi, CTRL, 0xf, 0xf, true);
    return x + __builtin_bit_cast(float, yi);
}
__device__ __forceinline__ float reduce16(float x) {
    x = dpp_add<0xB1>(x);          // quad xor1
    x = dpp_add<0x4E>(x);          // quad xor2
    x = dpp_add<0x124>(x);         // row_ror:4
    x = dpp_add<0x128>(x);         // row_ror:8
    return x;
}

// Overflow-free activations (r12/r13-verified numerics).
__device__ __forceinline__ float rcpf(float x) { return __builtin_amdgcn_rcpf(x); }
__device__ __forceinline__ float tanh_pos(float ax) {
    float t = __expf(-2.0f * ax);
    return (1.0f - t) * rcpf(1.0f + t);
}

// -------------------------------------------------------------------------
// Kernel 1 (ROUND-14 REWRITE): Xproj via MFMA f16.
//   out[m][n] = gate_b[n] + sum_k input[m][k] * gate_w[n][HID+k]
// C = A·B^T with A=[M][K] fp32 (input), B=[N][K] fp32 (gate_w x-slice),
// both converted to f16 and loaded into fragments with the SAME
// lane->(index, k-range) pattern (m91/m97-verified symmetric-load form;
// any k-permutation inside the fragment cancels in the dot product).
// C/D layout (HW-verified m89/m91): col = lane&15, row = (lane>>4)*4 + reg.
// Wave = 2 m-tiles (A-frags register-resident across the n-loop) so B is
// read 4096 waves x 512KB ~ 2.1GB from L2. Output stored as f16 scalars --
// exactly aliases the u32-packed xp16 layout the lstm kernel reads.
// -------------------------------------------------------------------------
__global__ __launch_bounds__(256, 4) void xproj_kernel(
    const float* __restrict__ input,
    const float* __restrict__ gate_w,
    const float* __restrict__ gate_b,
    _Float16* __restrict__ xph)        // [T*B][HID] f16 (= packed u32 words)
{
    const int w    = threadIdx.x >> 6;    // wave 0..3
    const int lane = threadIdx.x & 63;
    const int lr   = lane & 15;           // A-row / B-col within tile
    const int lg   = lane >> 4;           // k-subgroup 0..3
    const int m0a  = blockIdx.x * 128 + w * 32;   // first m-tile
    const int m0b  = m0a + 16;                    // second m-tile

    // A-fragments for both m-tiles, all 8 k-steps (fp32 -> f16, once)
    f16x8 afa[8], afb[8];
    {
        const float* ara = input + (size_t)(m0a + lr) * IN_SZ + lg * 8;
        const float* arb = input + (size_t)(m0b + lr) * IN_SZ + lg * 8;
        #pragma unroll
        for (int t = 0; t < 8; ++t) {
            float4 v0 = *(const float4*)(ara + t * 32);
            float4 v1 = *(const float4*)(ara + t * 32 + 4);
            afa[t] = f16x8{(_Float16)v0.x, (_Float16)v0.y, (_Float16)v0.z, (_Float16)v0.w,
                           (_Float16)v1.x, (_Float16)v1.y, (_Float16)v1.z, (_Float16)v1.w};
            float4 u0 = *(const float4*)(arb + t * 32);
            float4 u1 = *(const float4*)(arb + t * 32 + 4);
            afb[t] = f16x8{(_Float16)u0.x, (_Float16)u0.y, (_Float16)u0.z, (_Float16)u0.w,
                           (_Float16)u1.x, (_Float16)u1.y, (_Float16)u1.z, (_Float16)u1.w};
        }
    }

    for (int n0 = 0; n0 < HID; n0 += 16) {
        const float* br = gate_w + (size_t)(n0 + lr) * FANG + HID + lg * 8;
        f32x4 acc_a = {0.f, 0.f, 0.f, 0.f};
        f32x4 acc_b = {0.f, 0.f, 0.f, 0.f};
        #pragma unroll
        for (int t = 0; t < 8; ++t) {
            float4 v0 = *(const float4*)(br + t * 32);
            float4 v1 = *(const float4*)(br + t * 32 + 4);
            f16x8 bf = f16x8{(_Float16)v0.x, (_Float16)v0.y, (_Float16)v0.z, (_Float16)v0.w,
                             (_Float16)v1.x, (_Float16)v1.y, (_Float16)v1.z, (_Float16)v1.w};
            acc_a = __builtin_amdgcn_mfma_f32_16x16x32_f16(afa[t], bf, acc_a, 0, 0, 0);
            acc_b = __builtin_amdgcn_mfma_f32_16x16x32_f16(afb[t], bf, acc_b, 0, 0, 0);
        }
        const float gb = gate_b[n0 + lr];
        #pragma unroll
        for (int i = 0; i < 4; ++i) {
            const int ra = m0a + lg * 4 + i;       // C/D: row=(lane>>4)*4+reg
            const int rb = m0b + lg * 4 + i;
            xph[(size_t)ra * HID + n0 + lr] = (_Float16)(acc_a[i] + gb);
            xph[(size_t)rb * HID + n0 + lr] = (_Float16)(acc_b[i] + gb);
        }
    }
}

// -------------------------------------------------------------------------
// Kernel 2: recurrence — UNCHANGED from round 13 (proven, at its latency
// floor: r10/r11/r13 all pinned at ~2730 cy/step across three different
// VALU/LDS/barrier structures).
// -------------------------------------------------------------------------
__global__ __launch_bounds__(512, 2) void lstm_kernel(
    const float* __restrict__ gate_w,
    const u32* __restrict__ xp16,
    u64* __restrict__ hx)
{
    const int blk  = blockIdx.x;     // 0..255
    const int s    = blk >> 6;       // slice 0..3 (owns rows s*128..+128)
    const int b    = blk & 63;       // batch row
    const int tid  = threadIdx.x;    // 0..511
    const int g    = tid >> 4;       // row group 0..31
    const int c    = tid & 15;       // k-lane
    const int wv   = tid >> 6;       // wave 0..7
    const int lane = tid & 63;
    const int j0   = s * 128 + g * 4;

    __shared__ u32 hl[2][256];

    h2 w2[64];
    #pragma unroll
    for (int u = 0; u < 4; ++u) {
        const int kb = (((s + u) & 3) * 64 + c * 4) * 2;
        #pragma unroll
        for (int rr = 0; rr < 4; ++rr) {
            const float* wr = gate_w + (size_t)(j0 + rr) * FANG + kb;
            float4 v0 = *(const float4*)(wr);
            float4 v1 = *(const float4*)(wr + 4);
            w2[rr * 16 + u * 4 + 0] = h2{(_Float16)v0.x, (_Float16)v0.y};
            w2[rr * 16 + u * 4 + 1] = h2{(_Float16)v0.z, (_Float16)v0.w};
            w2[rr * 16 + u * 4 + 2] = h2{(_Float16)v1.x, (_Float16)v1.y};
            w2[rr * 16 + u * 4 + 3] = h2{(_Float16)v1.z, (_Float16)v1.w};
        }
    }

    const bool poller = (lane < 24);
    const int  pi  = wv * 24 + lane;
    const int  si  = pi >> 6;
    const int  qs  = si + (si >= s);
    const int  prw = qs * 64 + (pi & 63);

    if (tid < 256) hl[0][tid] = 0;

    float cval = 0.0f;

    for (int st = 0; st < TOT_STEPS; ++st) {
        const int t   = st & (T_STEPS - 1);
        const int buf = st & 1;

        u32 xw = 0;
        if (c < 4) xw = xp16[((size_t)t * BATCH + b) * 256 + s * 64 + g * 2 + (c >> 1)];

        const u64* pp = hx + ((size_t)buf * BATCH + b) * 256 + prw;
        u64 pv = 0;
        if (poller) pv = ld_llc(pp);

        wg_barrier();   // bar1

        float a0 = 0.f, a1 = 0.f, a2 = 0.f, a3 = 0.f;
        {
            float4 rv = *(const float4*)&hl[buf][s * 64 + c * 4];
            h2 x0 = bch2(rv.x), x1 = bch2(rv.y), x2 = bch2(rv.z), x3 = bch2(rv.w);
            a0 = dot2f(w2[ 0], x0, a0); a0 = dot2f(w2[ 1], x1, a0);
            a0 = dot2f(w2[ 2], x2, a0); a0 = dot2f(w2[ 3], x3, a0);
            a1 = dot2f(w2[16], x0, a1); a1 = dot2f(w2[17], x1, a1);
            a1 = dot2f(w2[18], x2, a1); a1 = dot2f(w2[19], x3, a1);
            a2 = dot2f(w2[32], x0, a2); a2 = dot2f(w2[33], x1, a2);
            a2 = dot2f(w2[34], x2, a2); a2 = dot2f(w2[35], x3, a2);
            a3 = dot2f(w2[48], x0, a3); a3 = dot2f(w2[49], x1, a3);
            a3 = dot2f(w2[50], x2, a3); a3 = dot2f(w2[51], x3, a3);
        }

        if (poller) {
            u64 v = pv;
            int spin = 0;
            while ((u32)(v >> 32) != (u32)st) {
                v = ld_llc(pp);
                if (++spin > (1 << 16)) break;
                if (spin > 64) __builtin_amdgcn_s_sleep(1);
            }
            hl[buf][prw] = (u32)v;
        }
        wg_barrier();   // bar2

        #pragma unroll
        for (int u = 1; u < 4; ++u) {
            float4 rv = *(const float4*)&hl[buf][((s + u) & 3) * 64 + c * 4];
            h2 x0 = bch2(rv.x), x1 = bch2(rv.y), x2 = bch2(rv.z), x3 = bch2(rv.w);
            a0 = dot2f(w2[     u*4+0], x0, a0); a0 = dot2f(w2[     u*4+1], x1, a0);
            a0 = dot2f(w2[     u*4+2], x2, a0); a0 = dot2f(w2[     u*4+3], x3, a0);
            a1 = dot2f(w2[16 + u*4+0], x0, a1); a1 = dot2f(w2[16 + u*4+1], x1, a1);
            a1 = dot2f(w2[16 + u*4+2], x2, a1); a1 = dot2f(w2[16 + u*4+3], x3, a1);
            a2 = dot2f(w2[32 + u*4+0], x0, a2); a2 = dot2f(w2[32 + u*4+1], x1, a2);
            a2 = dot2f(w2[32 + u*4+2], x2, a2); a2 = dot2f(w2[32 + u*4+3], x3, a2);
            a3 = dot2f(w2[48 + u*4+0], x0, a3); a3 = dot2f(w2[48 + u*4+1], x1, a3);
            a3 = dot2f(w2[48 + u*4+2], x2, a3); a3 = dot2f(w2[48 + u*4+3], x3, a3);
        }

        a0 = reduce16(a0);
        a1 = reduce16(a1);
        a2 = reduce16(a2);
        a3 = reduce16(a3);

        float hf = 0.0f;
        if (c < 4) {
            float p = (c == 0) ? a0 : (c == 1) ? a1 : (c == 2) ? a2 : a3;
            h2 xp = bch2u(xw);
            float gg = p + (float)((c & 1) ? xp.y : xp.x);
            float et = __expf(-gg);
            float sg = rcpf(1.0f + et);
            float ch = copysignf(tanh_pos(fabsf(gg)), gg);
            cval = (cval + ch) * sg;
            float th = copysignf(tanh_pos(fabsf(cval)), cval);
            hf = th * sg;
        }
        float hfo = __shfl_down(hf, 1);
        if (c == 0 || c == 2) {
            const int w = s * 64 + g * 2 + (c >> 1);
            u32 pk = packh2(hf, hfo);
            st_llc(hx + ((size_t)((st + 1) & 1) * BATCH + b) * 256 + w,
                   (u64)pk | ((u64)(u32)(st + 1) << 32));
            hl[buf ^ 1][w] = pk;
        }
    }
}

// -------------------------------------------------------------------------
// Kernel 3: output = h_final @ out_w.T + out_b (unchanged).
// -------------------------------------------------------------------------
__global__ __launch_bounds__(256) void out_kernel(
    const u64* __restrict__ hx,
    const float* __restrict__ out_w,
    const float* __restrict__ out_b,
    float* __restrict__ out)
{
    const int b  = blockIdx.x;    // 64
    const int jt = threadIdx.x;   // 256
    __shared__ float hrow[512];

    {
        u64 v = hx[(size_t)b * 256 + jt];
        h2 pr = bch2u((u32)v);
        hrow[2 * jt]     = (float)pr.x;
        hrow[2 * jt + 1] = (float)pr.y;
    }
    __syncthreads();

    float acc = out_b[jt];
    const float* wr = out_w + (size_t)jt * HID;
    #pragma unroll 8
    for (int k = 0; k < HID; ++k)
        acc += hrow[k] * wr[k];
    out[(size_t)b * IN_SZ + jt] = acc;
}

// -------------------------------------------------------------------------
extern "C" void kernel_launch(void* const* d_in, const int* in_sizes, int n_in,
                              void* d_out, int out_size, void* d_ws, size_t ws_size,
                              hipStream_t stream)
{
    const float* input  = (const float*)d_in[0];
    const float* gate_w = (const float*)d_in[1];
    const float* gate_b = (const float*)d_in[2];
    const float* out_w  = (const float*)d_in[3];
    const float* out_b  = (const float*)d_in[4];
    float* out = (float*)d_out;

    // ws layout: Xproj f16 [131072][512] (128 MB) | hx [2][64][256] u64 (256 KB)
    _Float16* xph = (_Float16*)d_ws;
    u32*      xp16 = (u32*)d_ws;           // same bytes, word = col pair
    const size_t xbytes = (size_t)T_STEPS * BATCH * HID * sizeof(_Float16);
    u64* hx = (u64*)((char*)d_ws + xbytes);

    // zero the exchange every launch: tag 0 == initial h = 0; graph replays
    // must never see stale tags.
    (void)hipMemsetAsync(hx, 0, (size_t)2 * BATCH * 256 * sizeof(u64), stream);

    xproj_kernel<<<1024, 256, 0, stream>>>(input, gate_w, gate_b, xph);
    lstm_kernel<<<256, 512, 0, stream>>>(gate_w, xp16, hx);
    out_kernel<<<64, 256, 0, stream>>>(hx, out_w, out_b, out);
}